// Round 6
// baseline (1488.102 us; speedup 1.0000x reference)
//
#include <hip/hip_runtime.h>
#include <stdint.h>

typedef unsigned short u16;
using half8   = __attribute__((ext_vector_type(8))) _Float16;
using float4v = __attribute__((ext_vector_type(4))) float;

#define L2E 1.4426950408889634f

__device__ inline float4v f4zero() { float4v z = {0.f, 0.f, 0.f, 0.f}; return z; }

__device__ inline u16 f2h(float f) {
  union { _Float16 h; u16 u; } v; v.h = (_Float16)f; return v.u;
}
__device__ inline float h2f(u16 u) {
  union { u16 u; _Float16 h; } v; v.u = u; return (float)v.h;
}

// async global->LDS, 16B/lane. LDS dest = wave-uniform base + lane*16 (HW).
__device__ inline void glds16(const u16* g, u16* lds_base, int lane) {
#if __has_builtin(__builtin_amdgcn_global_load_lds)
  (void)lane;
  __builtin_amdgcn_global_load_lds((const __attribute__((address_space(1))) void*)g,
                                   (__attribute__((address_space(3))) void*)lds_base,
                                   16, 0, 0);
#else
  *(uint4*)(lds_base + (size_t)lane * 8) = *(const uint4*)g;
#endif
}

__device__ inline void wave_fence_barrier() {
  __asm__ volatile("s_waitcnt vmcnt(0) lgkmcnt(0)" ::: "memory");
  __builtin_amdgcn_s_barrier();
}

// ---------------------------------------------------------------------------
// fp32 (K,N) row-major -> f16 (N,K) row-major, per-layer stride out_ls elems.
// ---------------------------------------------------------------------------
__global__ __launch_bounds__(256) void transpose_cast_kernel(
    const float* __restrict__ in, u16* __restrict__ out, int K, int N, size_t out_ls) {
  __shared__ float tile[32][33];
  const int tx = threadIdx.x & 31, ty = threadIdx.x >> 5;
  in  += (size_t)blockIdx.z * K * N;
  out += (size_t)blockIdx.z * out_ls;
  const int n  = blockIdx.x * 32 + tx;
  const int k0 = blockIdx.y * 32;
#pragma unroll
  for (int j = 0; j < 32; j += 8)
    tile[ty + j][tx] = in[(size_t)(k0 + ty + j) * N + n];
  __syncthreads();
  const int k = k0 + tx;
  const int n0 = blockIdx.x * 32;
#pragma unroll
  for (int j = 0; j < 32; j += 8)
    out[(size_t)(n0 + ty + j) * K + k] = f2h(tile[tx][ty + j]);
}

__global__ __launch_bounds__(256) void cast_kernel(const float* __restrict__ in,
                                                   u16* __restrict__ out) {
  const int i = (blockIdx.x * 256 + threadIdx.x) * 4;
  float4 t = *(const float4*)(in + i);
  ushort4 o;
  o.x = f2h(t.x); o.y = f2h(t.y); o.z = f2h(t.z); o.w = f2h(t.w);
  *(ushort4*)(out + i) = o;
}

// pb fp32 (1,8,2048,2048) -> pbT f16 [h][kb][qg][lane][16], idx=nb*4+r, *L2E.
// One thread = 8 f16 (one b128 half). threads = 4,194,304.
__global__ __launch_bounds__(256) void pb_tile2_kernel(const float* __restrict__ pb,
                                                       u16* __restrict__ pbT) {
  const int g    = blockIdx.x * 256 + threadIdx.x;
  const int half = g & 1;
  const int lane = (g >> 1) & 63;
  const int qg   = (g >> 7) & 127;
  const int kb   = (g >> 14) & 31;
  const int h    = g >> 19;
  const int quad = lane >> 4, mm = lane & 15;
  ushort4 o[2];
  u16* op = (u16*)o;
#pragma unroll
  for (int e = 0; e < 8; e++) {
    const int nb = half * 2 + (e >> 2), r = e & 3;
    const int q = qg * 16 + quad * 4 + r;
    const int k = kb * 64 + nb * 16 + mm;
    op[e] = f2h(pb[((size_t)h * 2048 + q) * 2048 + k] * L2E);
  }
  *(uint4*)(pbT + ((((size_t)h * 32 + kb) * 128 + qg) * 64 + lane) * 16 + half * 8) =
      *(uint4*)o;
}

// lag-scale inv -> invT f16 [b][kb][qg][lane][16], idx=nb*4+r, *L2E folded.
// inv = (u+60000)/(9u+480000), u = max(tq-tk,0). threads = 2,097,152.
__global__ __launch_bounds__(256) void inv_tile2_kernel(const int* __restrict__ ts,
                                                        u16* __restrict__ invT) {
  const int g    = blockIdx.x * 256 + threadIdx.x;
  const int half = g & 1;
  const int lane = (g >> 1) & 63;
  const int qg   = (g >> 7) & 127;
  const int kb   = (g >> 14) & 31;
  const int b    = g >> 19;
  const int quad = lane >> 4, mm = lane & 15;
  int tq[4], tk[2];
#pragma unroll
  for (int r = 0; r < 4; r++) tq[r] = ts[b * 2048 + qg * 16 + quad * 4 + r];
#pragma unroll
  for (int n = 0; n < 2; n++) tk[n] = ts[b * 2048 + kb * 64 + (half * 2 + n) * 16 + mm];
  ushort4 o[2];
  u16* op = (u16*)o;
#pragma unroll
  for (int e = 0; e < 8; e++) {
    const int n = e >> 2, r = e & 3;
    const int du = tq[r] - tk[n];
    const float u = (du > 0) ? (float)du : 0.f;
    op[e] = f2h(fmaf(u, L2E, 86561.70245333781f) *
                __builtin_amdgcn_rcpf(fmaf(u, 9.f, 480000.f)));
  }
  *(uint4*)(invT + ((((size_t)b * 32 + kb) * 128 + qg) * 64 + lane) * 16 + half * 8) =
      *(uint4*)o;
}

__global__ __launch_bounds__(256) void maskts_kernel(const float* __restrict__ mask,
                                                     const int* __restrict__ ts,
                                                     float* __restrict__ maskE,
                                                     float* __restrict__ tsf) {
  const int i = blockIdx.x * 256 + threadIdx.x;
  maskE[i] = mask[i] * L2E;
  tsf[i]   = (float)ts[i];
}

// ---------------------------------------------------------------------------
// GEMM (2-barrier, single-buffer) for EPI 3/4. BMxBN tile, BK=64, f16 MFMA.
// EPI: 3 = gelu(acc+bias) f16; 4 = fused QKV scatter.
// ---------------------------------------------------------------------------
template <int BM, int BN, int NN, int KK, int EPI>
__global__ __launch_bounds__(256) void gemm_kernel(
    const u16* __restrict__ A, const u16* __restrict__ Wt,
    const float* __restrict__ b0, const float* __restrict__ b1, const float* __restrict__ b2,
    void* __restrict__ o0, void* __restrict__ o1, void* __restrict__ o2) {
  constexpr int FI = BM / 32;
  constexpr int FJB = BN / 32;
  constexpr int FIW = BM / 32;
  constexpr int FJW = BN / 32;
  __shared__ __align__(16) u16 As[BM * 64];
  __shared__ __align__(16) u16 Bs[BN * 64];
  const int tid = threadIdx.x, lane = tid & 63, wv = tid >> 6;
  const int quad = lane >> 4, mm = lane & 15;
  const int m0 = blockIdx.x * BM, n0 = blockIdx.y * BN;
  const int wm = (wv >> 1) * (BM / 2), wn = (wv & 1) * (BN / 2);
  const int srow = tid >> 3, slot = tid & 7;
  const int chunk = slot ^ (srow & 7);
  const u16* Ag = A  + (size_t)(m0 + srow) * KK + chunk * 8;
  const u16* Bg = Wt + (size_t)(n0 + srow) * KK + chunk * 8;
  u16* AsW = As + (size_t)(wv * 8) * 64;
  u16* BsW = Bs + (size_t)(wv * 8) * 64;
  const int sw = mm & 7;

  float4v acc[FIW][FJW];
#pragma unroll
  for (int i = 0; i < FIW; i++)
#pragma unroll
    for (int j = 0; j < FJW; j++) acc[i][j] = f4zero();

  for (int kt = 0; kt < KK; kt += 64) {
#pragma unroll
    for (int i = 0; i < FI; i++)
      glds16(Ag + (size_t)i * 32 * KK + kt, AsW + i * 32 * 64, lane);
#pragma unroll
    for (int j = 0; j < FJB; j++)
      glds16(Bg + (size_t)j * 32 * KK + kt, BsW + j * 32 * 64, lane);
    __syncthreads();
#pragma unroll
    for (int ks = 0; ks < 2; ks++) {
      half8 a[FIW], b[FJW];
#pragma unroll
      for (int i = 0; i < FIW; i++)
        a[i] = *(const half8*)(As + (size_t)(wm + i * 16 + mm) * 64 + (size_t)((ks * 4 + quad) ^ sw) * 8);
#pragma unroll
      for (int j = 0; j < FJW; j++)
        b[j] = *(const half8*)(Bs + (size_t)(wn + j * 16 + mm) * 64 + (size_t)((ks * 4 + quad) ^ sw) * 8);
#pragma unroll
      for (int i = 0; i < FIW; i++)
#pragma unroll
        for (int j = 0; j < FJW; j++)
          acc[i][j] = __builtin_amdgcn_mfma_f32_16x16x32_f16(a[i], b[j], acc[i][j], 0, 0, 0);
    }
    __syncthreads();
  }

#pragma unroll
  for (int j = 0; j < FJW; j++) {
    const int gn = n0 + wn + j * 16 + mm;
    if (EPI == 4) {
      const int which = gn >> 9, col = gn & 511, h = (gn >> 6) & 7, d = gn & 63;
      const float* bp = (which == 0) ? b0 : (which == 1) ? b1 : b2;
      const float bias = bp[col];
      u16* dst = (which == 0) ? (u16*)o0 : (which == 1) ? (u16*)o1 : (u16*)o2;
#pragma unroll
      for (int i = 0; i < FIW; i++)
#pragma unroll
        for (int r = 0; r < 4; r++) {
          const int gm = m0 + wm + i * 16 + quad * 4 + r;
          const int b_ = gm >> 11, s_ = gm & 2047;
          const float val = acc[i][j][r] + bias;
          if (which < 2)
            dst[((size_t)((b_ * 8 + h) * 2048 + s_)) * 64 + d] = f2h(val);
          else
            dst[((size_t)((b_ * 8 + h) * 64 + d)) * 2048 + s_] = f2h(val);
        }
    } else {  // EPI == 3: exact-erf GELU -> f16
      const float bias = b0[gn];
#pragma unroll
      for (int i = 0; i < FIW; i++)
#pragma unroll
        for (int r = 0; r < 4; r++) {
          const int gm = m0 + wm + i * 16 + quad * 4 + r;
          const float val = acc[i][j][r] + bias;
          const size_t idx = (size_t)gm * NN + gn;
          const float z  = val * 0.70710678118654752f;
          const float az = fabsf(z);
          const float t  = __builtin_amdgcn_rcpf(1.0f + 0.3275911f * az);
          const float poly = t * (0.254829592f + t * (-0.284496736f +
                             t * (1.421413741f + t * (-1.453152027f + t * 1.061405429f))));
          const float e = __builtin_amdgcn_exp2f(-az * az * L2E);
          float erf_ = 1.0f - poly * e;
          erf_ = (z < 0.0f) ? -erf_ : erf_;
          ((u16*)o0)[idx] = f2h(val * 0.5f * (1.0f + erf_));
        }
    }
  }
}

// ---------------------------------------------------------------------------
// GEMM with single-barrier double-buffered staging (BM=128, BN=64, NN=512).
// out f16 = acc + bias + f16 resid.
// ---------------------------------------------------------------------------
template <int KK>
__global__ __launch_bounds__(256) void gemm_db_kernel(
    const u16* __restrict__ A, const u16* __restrict__ Wt,
    const float* __restrict__ b0, const u16* __restrict__ resid,
    u16* __restrict__ out) {
  constexpr int KT = KK / 64;
  __shared__ __align__(16) u16 As[2][128 * 64];
  __shared__ __align__(16) u16 Bs[2][64 * 64];
  const int tid = threadIdx.x, lane = tid & 63, wv = tid >> 6;
  const int quad = lane >> 4, mm = lane & 15;
  const int m0 = blockIdx.x * 128, n0 = blockIdx.y * 64;
  const int wm = (wv >> 1) * 64, wn = (wv & 1) * 32;
  const int srow = tid >> 3, slot = tid & 7;
  const int chunk = slot ^ (srow & 7);
  const u16* Ag = A  + (size_t)(m0 + srow) * KK + chunk * 8;
  const u16* Bg = Wt + (size_t)(n0 + srow) * KK + chunk * 8;
  const int woff = (wv * 8) * 64;
  const int sw = mm & 7;

  float4v acc[4][2];
#pragma unroll
  for (int i = 0; i < 4; i++)
#pragma unroll
    for (int j = 0; j < 2; j++) acc[i][j] = f4zero();

  // stage tile 0
#pragma unroll
  for (int i = 0; i < 4; i++) glds16(Ag + (size_t)i * 32 * KK, As[0] + woff + i * 32 * 64, lane);
#pragma unroll
  for (int j = 0; j < 2; j++) glds16(Bg + (size_t)j * 32 * KK, Bs[0] + woff + j * 32 * 64, lane);
  wave_fence_barrier();

  for (int t = 0; t < KT; t++) {
    const int cur = t & 1;
    if (t + 1 < KT) {
      const int kt = (t + 1) * 64;
#pragma unroll
      for (int i = 0; i < 4; i++)
        glds16(Ag + (size_t)i * 32 * KK + kt, As[cur ^ 1] + woff + i * 32 * 64, lane);
#pragma unroll
      for (int j = 0; j < 2; j++)
        glds16(Bg + (size_t)j * 32 * KK + kt, Bs[cur ^ 1] + woff + j * 32 * 64, lane);
    }
#pragma unroll
    for (int ks = 0; ks < 2; ks++) {
      half8 a[4], b[2];
#pragma unroll
      for (int i = 0; i < 4; i++)
        a[i] = *(const half8*)(As[cur] + (size_t)(wm + i * 16 + mm) * 64 + (size_t)((ks * 4 + quad) ^ sw) * 8);
#pragma unroll
      for (int j = 0; j < 2; j++)
        b[j] = *(const half8*)(Bs[cur] + (size_t)(wn + j * 16 + mm) * 64 + (size_t)((ks * 4 + quad) ^ sw) * 8);
#pragma unroll
      for (int i = 0; i < 4; i++)
#pragma unroll
        for (int j = 0; j < 2; j++)
          acc[i][j] = __builtin_amdgcn_mfma_f32_16x16x32_f16(a[i], b[j], acc[i][j], 0, 0, 0);
    }
    wave_fence_barrier();
  }

#pragma unroll
  for (int j = 0; j < 2; j++) {
    const int gn = n0 + wn + j * 16 + mm;
    const float bias = b0[gn];
#pragma unroll
    for (int i = 0; i < 4; i++)
#pragma unroll
      for (int r = 0; r < 4; r++) {
        const int gm = m0 + wm + i * 16 + quad * 4 + r;
        const size_t idx = (size_t)gm * 512 + gn;
        out[idx] = f2h(acc[i][j][r] + bias + h2f(resid[idx]));
      }
  }
}

// ---------------------------------------------------------------------------
// Flash v5: single-barrier double-buffered K/V staging, consolidated pbT/invT
// b128 operand loads (prefetched 1 tile ahead), P stride-64 XOR swizzle.
// grid (32, 32), block 256 (4 waves x 16 q). LDS = 40960 B -> 4 blocks/CU.
// TILED: 2 = pbT+invT tensors; 0 = raw pb32 + on-the-fly inv (fallback).
// ---------------------------------------------------------------------------
template <int TILED>
__global__ __launch_bounds__(256) void flash5_kernel(
    const u16* __restrict__ Q, const u16* __restrict__ Kb, const u16* __restrict__ Vt,
    const u16* __restrict__ pbT, const u16* __restrict__ invT,
    const float* __restrict__ pb32,
    const float* __restrict__ maskE, const float* __restrict__ tsf,
    u16* __restrict__ ctx) {
  __shared__ __align__(16) u16 Kls[2][64 * 64];
  __shared__ __align__(16) u16 Vls[2][64 * 64];
  __shared__ __align__(16) u16 P[4][16 * 64];
  const int tid = threadIdx.x, lane = tid & 63, w = tid >> 6;
  const int quad = lane >> 4, mm = lane & 15;
  const int bh = blockIdx.y, b_ = bh >> 3, h_ = bh & 7;
  const int qg = blockIdx.x * 4 + w;       // 16-row q group
  const int q0 = qg * 16;
  const size_t qk_base = (size_t)bh * 2048 * 64;
  const size_t v_base  = (size_t)bh * 64 * 2048;
  const int srow = lane >> 3, slot = lane & 7;
  const int chunk = slot ^ srow;
  const int sw = mm & 7;

  half8 aq[2];
#pragma unroll
  for (int t = 0; t < 2; t++)
    aq[t] = *(const half8*)(Q + qk_base + (size_t)(q0 + mm) * 64 + t * 32 + quad * 8);

  float tqf[4];
  if (TILED == 0) {
#pragma unroll
    for (int r = 0; r < 4; r++) tqf[r] = tsf[b_ * 2048 + q0 + quad * 4 + r];
  }

  float l_r[4] = {0.f, 0.f, 0.f, 0.f};
  float4v o[4];
#pragma unroll
  for (int ob = 0; ob < 4; ob++) o[ob] = f4zero();

  // stage tile 0 + prefetch tile-0 operands
#pragma unroll
  for (int i = 0; i < 2; i++) {
    const int row = w * 16 + i * 8 + srow;
    glds16(Kb + qk_base + (size_t)row * 64 + chunk * 8, Kls[0] + (w * 16 + i * 8) * 64, lane);
    glds16(Vt + v_base + (size_t)row * 2048 + chunk * 8, Vls[0] + (w * 16 + i * 8) * 64, lane);
  }
  half8 pbc[2], invc[2];
  float tkc[4], mkc[4];
  if (TILED == 2) {
    const size_t pbb = (((size_t)h_ * 32 + 0) * 128 + qg) * 1024 + lane * 16;
    const size_t ivb = (((size_t)b_ * 32 + 0) * 128 + qg) * 1024 + lane * 16;
    pbc[0] = *(const half8*)(pbT + pbb);     pbc[1] = *(const half8*)(pbT + pbb + 8);
    invc[0] = *(const half8*)(invT + ivb);   invc[1] = *(const half8*)(invT + ivb + 8);
  } else {
#pragma unroll
    for (int nb = 0; nb < 4; nb++) tkc[nb] = tsf[b_ * 2048 + nb * 16 + mm];
  }
#pragma unroll
  for (int nb = 0; nb < 4; nb++) mkc[nb] = maskE[b_ * 2048 + nb * 16 + mm];
  wave_fence_barrier();

  for (int kt = 0; kt < 32; kt++) {
    const int cur = kt & 1;
    half8 pbn[2], invn[2];
    float tkn[4], mkn[4];
    if (kt < 31) {
      const int k1 = (kt + 1) * 64;
#pragma unroll
      for (int i = 0; i < 2; i++) {
        const int row = w * 16 + i * 8 + srow;
        glds16(Kb + qk_base + (size_t)(k1 + row) * 64 + chunk * 8,
               Kls[cur ^ 1] + (w * 16 + i * 8) * 64, lane);
        glds16(Vt + v_base + (size_t)row * 2048 + k1 + chunk * 8,
               Vls[cur ^ 1] + (w * 16 + i * 8) * 64, lane);
      }
      if (TILED == 2) {
        const size_t pbb = (((size_t)h_ * 32 + kt + 1) * 128 + qg) * 1024 + lane * 16;
        const size_t ivb = (((size_t)b_ * 32 + kt + 1) * 128 + qg) * 1024 + lane * 16;
        pbn[0] = *(const half8*)(pbT + pbb);   pbn[1] = *(const half8*)(pbT + pbb + 8);
        invn[0] = *(const half8*)(invT + ivb); invn[1] = *(const half8*)(invT + ivb + 8);
      } else {
#pragma unroll
        for (int nb = 0; nb < 4; nb++) tkn[nb] = tsf[b_ * 2048 + (kt + 1) * 64 + nb * 16 + mm];
      }
#pragma unroll
      for (int nb = 0; nb < 4; nb++) mkn[nb] = maskE[b_ * 2048 + (kt + 1) * 64 + nb * 16 + mm];
    }

    // QK^T from LDS
    float4v s[4];
#pragma unroll
    for (int nb = 0; nb < 4; nb++) {
      const half8 kf0 = *(const half8*)(Kls[cur] + (size_t)(nb * 16 + mm) * 64 + (size_t)(quad ^ sw) * 8);
      const half8 kf1 = *(const half8*)(Kls[cur] + (size_t)(nb * 16 + mm) * 64 + (size_t)((4 + quad) ^ sw) * 8);
      s[nb] = __builtin_amdgcn_mfma_f32_16x16x32_f16(aq[0], kf0, f4zero(), 0, 0, 0);
      s[nb] = __builtin_amdgcn_mfma_f32_16x16x32_f16(aq[1], kf1, s[nb], 0, 0, 0);
    }

    // softmax + P write (P[row=quad*4+r][col=nb*16+mm], stride 64, XOR chunks)
    const int rw7 = (quad * 4) & 7;
#pragma unroll
    for (int r = 0; r < 4; r++) {
      const int prow = quad * 4 + r;
#pragma unroll
      for (int nb = 0; nb < 4; nb++) {
        float pbv, iv;
        if (TILED == 2) {
          pbv = (float)pbc[nb >> 1][(nb & 1) * 4 + r];
          iv  = (float)invc[nb >> 1][(nb & 1) * 4 + r];
        } else {
          pbv = pb32[((size_t)h_ * 2048 + q0 + prow) * 2048 + kt * 64 + nb * 16 + mm] * L2E;
          const float u = fmaxf(tqf[r] - tkc[nb], 0.f);
          iv = fmaf(u, L2E, 86561.70245333781f) *
               __builtin_amdgcn_rcpf(fmaf(u, 9.f, 480000.f));
        }
        const float t = fmaf(s[nb][r], iv, pbv + mkc[nb]);
        const float p = __builtin_amdgcn_exp2f(t);
        l_r[r] += p;
        const int pslot = (nb * 2 + (mm >> 3)) ^ ((rw7 + r) & 7);
        P[w][prow * 64 + pslot * 8 + (mm & 7)] = f2h(p);
      }
    }

    // PV from LDS
    const half8 ap0 = *(const half8*)(&P[w][mm * 64 + (size_t)(quad ^ sw) * 8]);
    const half8 ap1 = *(const half8*)(&P[w][mm * 64 + (size_t)((4 + quad) ^ sw) * 8]);
#pragma unroll
    for (int ob = 0; ob < 4; ob++) {
      const half8 vf0 = *(const half8*)(Vls[cur] + (size_t)(ob * 16 + mm) * 64 + (size_t)(quad ^ sw) * 8);
      const half8 vf1 = *(const half8*)(Vls[cur] + (size_t)(ob * 16 + mm) * 64 + (size_t)((4 + quad) ^ sw) * 8);
      o[ob] = __builtin_amdgcn_mfma_f32_16x16x32_f16(ap0, vf0, o[ob], 0, 0, 0);
      o[ob] = __builtin_amdgcn_mfma_f32_16x16x32_f16(ap1, vf1, o[ob], 0, 0, 0);
    }

    wave_fence_barrier();
    if (kt < 31) {
#pragma unroll
      for (int i = 0; i < 2; i++) { pbc[i] = pbn[i]; invc[i] = invn[i]; }
#pragma unroll
      for (int nb = 0; nb < 4; nb++) { tkc[nb] = tkn[nb]; mkc[nb] = mkn[nb]; }
    }
  }

#pragma unroll
  for (int r = 0; r < 4; r++) {
    float l = l_r[r];
#pragma unroll
    for (int sh = 1; sh < 16; sh <<= 1) l += __shfl_xor(l, sh, 64);  // sum over mm
    const float rl = __builtin_amdgcn_rcpf(l);
    const int qrow = q0 + quad * 4 + r;
#pragma unroll
    for (int ob = 0; ob < 4; ob++)
      ctx[((size_t)b_ * 2048 + qrow) * 512 + h_ * 64 + ob * 16 + mm] = f2h(o[ob][r] * rl);
  }
}

// ---------------------------------------------------------------------------
// LayerNorm over H=512 (f16 input): 1 wave/row, 4 rows/block.
// ---------------------------------------------------------------------------
__global__ __launch_bounds__(256) void ln_kernel(
    const u16* __restrict__ in, const float* __restrict__ g, const float* __restrict__ bb,
    float* __restrict__ of, u16* __restrict__ obf) {
  const int lane = threadIdx.x & 63, w = threadIdx.x >> 6;
  const int row = blockIdx.x * 4 + w;
  const half8 hv = *(const half8*)(in + (size_t)row * 512 + lane * 8);
  float v[8];
#pragma unroll
  for (int i = 0; i < 8; i++) v[i] = (float)hv[i];
  float s = 0.f;
#pragma unroll
  for (int i = 0; i < 8; i++) s += v[i];
#pragma unroll
  for (int sh = 1; sh < 64; sh <<= 1) s += __shfl_xor(s, sh, 64);
  const float mean = s * (1.0f / 512.0f);
  float sq = 0.f;
#pragma unroll
  for (int i = 0; i < 8; i++) { const float d = v[i] - mean; sq += d * d; }
#pragma unroll
  for (int sh = 1; sh < 64; sh <<= 1) sq += __shfl_xor(sq, sh, 64);
  const float rstd = rsqrtf(sq * (1.0f / 512.0f) + 1e-12f);
#pragma unroll
  for (int i = 0; i < 8; i++) {
    const int col = lane * 8 + i;
    const float y = (v[i] - mean) * rstd * g[col] + bb[col];
    if (of) of[(size_t)row * 512 + col] = y;
    obf[(size_t)row * 512 + col] = f2h(y);
  }
}

// ---------------------------------------------------------------------------
extern "C" void kernel_launch(void* const* d_in, const int* in_sizes, int n_in,
                              void* d_out, int out_size, void* d_ws, size_t ws_size,
                              hipStream_t stream) {
  const float* x_in = (const float*)d_in[0];
  const float* mask = (const float*)d_in[1];
  const float* pb   = (const float*)d_in[2];
  const int*   ts   = (const int*)d_in[3];
  const float* wq = (const float*)d_in[4];  const float* bq = (const float*)d_in[5];
  const float* wk = (const float*)d_in[6];  const float* bk = (const float*)d_in[7];
  const float* wvp = (const float*)d_in[8]; const float* bv = (const float*)d_in[9];
  const float* wo = (const float*)d_in[10]; const float* bo = (const float*)d_in[11];
  const float* ln1g = (const float*)d_in[12]; const float* ln1b = (const float*)d_in[13];
  const float* wi = (const float*)d_in[14]; const float* bi = (const float*)d_in[15];
  const float* wo2 = (const float*)d_in[16]; const float* bo2 = (const float*)d_in[17];
  const float* ln2g = (const float*)d_in[18]; const float* ln2b = (const float*)d_in[19];

  char* ws = (char*)d_ws;
  const size_t o_wqkv  = 0;
  const size_t o_woT   = 6291456;
  const size_t o_wiT   = 8388608;
  const size_t o_wo2T  = 16777216;
  const size_t o_maskE = 25165824;
  const size_t o_tsf   = 25198592;
  const size_t o_xbf   = 25231360;
  const size_t o_qb    = 33619968;
  const size_t o_kb    = 42008576;
  const size_t o_vb    = 50397184;
  const size_t o_ctx   = 58785792;
  const size_t o_attnb = 67174400;
  const size_t o_tmp   = 75563008;
  const size_t o_pbT   = 92340224;    // 67,108,864 B
  const size_t o_invT  = 159449088;   // 33,554,432 B
  const int tiled = (ws_size >= o_invT + 33554432ull) ? 2 : 0;

  u16*   wqkvT = (u16*)(ws + o_wqkv);
  u16*   woT   = (u16*)(ws + o_woT);
  u16*   wiT   = (u16*)(ws + o_wiT);
  u16*   wo2T  = (u16*)(ws + o_wo2T);
  float* maskE = (float*)(ws + o_maskE);
  float* tsf   = (float*)(ws + o_tsf);
  u16*   xbf   = (u16*)(ws + o_xbf);
  u16*   qb    = (u16*)(ws + o_qb);
  u16*   kb    = (u16*)(ws + o_kb);
  u16*   vb    = (u16*)(ws + o_vb);
  u16*   ctx   = (u16*)(ws + o_ctx);
  u16*   hb    = (u16*)(ws + o_qb);
  u16*   attnb = (u16*)(ws + o_attnb);
  u16*   tmp16 = (u16*)(ws + o_tmp);
  u16*   pbT   = (u16*)(ws + o_pbT);
  u16*   invT  = (u16*)(ws + o_invT);

  const dim3 blk(256);
  transpose_cast_kernel<<<dim3(16, 16, 4), blk, 0, stream>>>(wq,  wqkvT,          512, 512, 786432);
  transpose_cast_kernel<<<dim3(16, 16, 4), blk, 0, stream>>>(wk,  wqkvT + 262144, 512, 512, 786432);
  transpose_cast_kernel<<<dim3(16, 16, 4), blk, 0, stream>>>(wvp, wqkvT + 524288, 512, 512, 786432);
  transpose_cast_kernel<<<dim3(16, 16, 4), blk, 0, stream>>>(wo,  woT,  512, 512,  262144);
  transpose_cast_kernel<<<dim3(64, 16, 4), blk, 0, stream>>>(wi,  wiT,  512, 2048, 1048576);
  transpose_cast_kernel<<<dim3(16, 64, 4), blk, 0, stream>>>(wo2, wo2T, 2048, 512, 1048576);
  maskts_kernel<<<32, blk, 0, stream>>>(mask, ts, maskE, tsf);
  cast_kernel<<<4096, blk, 0, stream>>>(x_in, xbf);
  if (tiled == 2) {
    pb_tile2_kernel<<<16384, blk, 0, stream>>>(pb, pbT);
    inv_tile2_kernel<<<8192, blk, 0, stream>>>(ts, invT);
  }

  for (int l = 0; l < 4; l++) {
    gemm_kernel<128, 128, 1536, 512, 4><<<dim3(64, 12), blk, 0, stream>>>(
        xbf, wqkvT + (size_t)l * 786432, bq + l * 512, bk + l * 512, bv + l * 512,
        qb, kb, vb);
    if (tiled == 2)
      flash5_kernel<2><<<dim3(32, 32), blk, 0, stream>>>(qb, kb, vb, pbT, invT, pb, maskE, tsf, ctx);
    else
      flash5_kernel<0><<<dim3(32, 32), blk, 0, stream>>>(qb, kb, vb, nullptr, nullptr, pb, maskE, tsf, ctx);
    gemm_db_kernel<512><<<dim3(64, 8), blk, 0, stream>>>(
        ctx, woT + (size_t)l * 262144, bo + l * 512, xbf, tmp16);
    ln_kernel<<<2048, blk, 0, stream>>>(tmp16, ln1g + l * 512, ln1b + l * 512, nullptr, attnb);
    gemm_kernel<128, 128, 2048, 512, 3><<<dim3(64, 16), blk, 0, stream>>>(
        attnb, wiT + (size_t)l * 1048576, bi + l * 2048, nullptr, nullptr,
        hb, nullptr, nullptr);
    gemm_db_kernel<2048><<<dim3(64, 8), blk, 0, stream>>>(
        hb, wo2T + (size_t)l * 1048576, bo2 + l * 512, attnb, tmp16);
    ln_kernel<<<2048, blk, 0, stream>>>(tmp16, ln2g + l * 512, ln2b + l * 512,
                                        (l == 3) ? (float*)d_out : nullptr, xbf);
  }
  (void)in_sizes; (void)n_in; (void)out_size;
}